// Round 6
// baseline (1158.185 us; speedup 1.0000x reference)
//
#include <hip/hip_runtime.h>
#include <hip/hip_cooperative_groups.h>
#include <math.h>

namespace cg = cooperative_groups;

#define GG     384
#define HALFG  192
#define SZc    384
#define SYZc   147456
#define SXYZc  56623104
#define CC     128
#define PP     343
#define KK     125
#define TBSLOTS (1 << 20)
#define TBMASK  (TBSLOTS - 1)
#define EMPTYB  0xFFFFFFFFu
#define CHSLOTS (1 << 19)
#define CHMASK  (CHSLOTS - 1)
#define EMPTYU  0xFFFFFFFFu
#define TASLOTS (1 << 19)
#define TAMASK  (TASLOTS - 1)
#define NBLKA   (TASLOTS / 256)   // 2048
#define CAPK   2048
#define CAPP   1024
#define EPSc   1e-5f

typedef unsigned long long u64;

struct MegaP {
    const int4* spc4; const float* spf; const float* gp;
    const float* W1; const float* g1; const float* b1;
    const float* W2; const float* g2; const float* b2;
    float* out;
    unsigned* tabB; unsigned* colKV; int2* tabA;
    u64* colBM;
    int* cntk; int* pcnt; float* gsum; float* gsumsq;
    int* hmark; float* pooled;
    int* blockCnt; int* bcntH;
    int* hitList; int* ucode; int* slotA;
    int* bkUid; int* bkP; int* pairPack;
    float* acc;
    int Nv, N, NB;
};

__device__ __forceinline__ unsigned hash32(int code) {
    unsigned h = (unsigned)code;
    h ^= h >> 16; h *= 0x7feb352du;
    h ^= h >> 15; h *= 0x846ca68bu;
    h ^= h >> 16;
    return h;
}

__device__ __forceinline__ void d_build(const MegaP& p, int i) {
    int4 s = p.spc4[i];
    int b = s.x;
    int x = (s.y >> 1) + HALFG;
    int y = (s.z >> 1) + HALFG;
    int z = (s.w >> 1) + HALFG;
    int code = b * SXYZc + x * SYZc + y * SZc + z;
    unsigned h = hash32(code);
    unsigned slot = h & TBMASK;
    unsigned val = ((h >> 18) << 18) | (unsigned)i;
    while (true) {
        unsigned old = atomicCAS(&p.tabB[slot], EMPTYB, val);
        if (old == EMPTYB) break;
        slot = (slot + 1) & TBMASK;
    }
    unsigned ccode = (unsigned)((b * GG + x) * GG + y);
    unsigned cs = hash32((int)ccode) & CHMASK;
    int cid;
    while (true) {
        unsigned old = atomicCAS(&p.colKV[cs], EMPTYU, ccode);
        if (old == EMPTYU || old == ccode) { cid = (int)cs; break; }
        cs = (cs + 1) & CHMASK;
    }
    atomicOr(&p.colBM[(size_t)cid * 6 + (z >> 6)], 1ull << (z & 63));
}

__device__ __forceinline__ void d_insertA(const MegaP& p, int i) {
    float4 g = ((const float4*)p.gp)[i];
    int b = (int)g.x;
    int vx = (int)floorf(g.y / 0.08f); vx = min(max(vx, -(HALFG - 1)), HALFG - 1);
    int vy = (int)floorf(g.z / 0.08f); vy = min(max(vy, -(HALFG - 1)), HALFG - 1);
    int vz = (int)floorf(g.w / 0.08f); vz = min(max(vz, -(HALFG - 1)), HALFG - 1);
    int code = b * SXYZc + (vx + HALFG) * SYZc + (vy + HALFG) * SZc + (vz + HALFG);
    unsigned h = hash32(code) & TAMASK;
    while (true) {
        int old = atomicCAS(&p.tabA[h].x, -1, code);
        if (old == -1 || old == code) break;
        h = (h + 1) & TAMASK;
    }
    p.slotA[i] = (int)h;
}

__device__ __forceinline__ void d_probe(const MegaP& p, unsigned uid, int c) {
    unsigned code = (unsigned)p.ucode[uid];
    unsigned b = code / SXYZc; unsigned rem = code - b * SXYZc;
    int x = (int)(rem / SYZc); rem -= (unsigned)x * SYZc;
    int y = (int)(rem / SZc);
    int z = (int)(rem - (unsigned)y * SZc);
    int dx = c / 5, dy = c - dx * 5;
    int cx = x + dx - 2, cy = y + dy - 2;
    if ((unsigned)cx >= GG || (unsigned)cy >= GG) return;
    unsigned ccode = (unsigned)(((int)b * GG + cx) * GG + cy);
    unsigned cs = hash32((int)ccode) & CHMASK;
    int cid = -1;
    while (true) {
        unsigned e = p.colKV[cs];
        if (e == EMPTYU) return;
        if (e == ccode) { cid = (int)cs; break; }
        cs = (cs + 1) & CHMASK;
    }
    int lo = max(z - 2, 0);
    int hi = min(z + 2, GG - 1);
    int width = hi - lo + 1;
    int i0 = lo >> 6, sh = lo & 63;
    const u64* bm = p.colBM + (size_t)cid * 6;
    u64 w = bm[i0] >> sh;
    if (sh + width > 64) w |= bm[i0 + 1] << (64 - sh);
    unsigned bits = (unsigned)(w & ((1ull << width) - 1ull));
    if (bits == 0) return;
    p.hmark[uid] = 1;
    int zbase = z - 2;
    while (bits) {
        int j = __builtin_ctz(bits);
        bits &= bits - 1;
        int tz = lo + j;
        int dz = tz - zbase;
        int k = c * 5 + dz;
        int tcode = (int)b * SXYZc + cx * SYZc + cy * SZc + tz;
        unsigned h = hash32(tcode);
        unsigned slot = h & TBMASK;
        unsigned tag = h >> 18;
        while (true) {
            unsigned v = p.tabB[slot];
            if (v == EMPTYB) break;
            if ((v >> 18) == tag) {
                int row = (int)(v & 0x3FFFFu);
                int4 s = p.spc4[row];
                int rcode = s.x * SXYZc + ((s.y >> 1) + HALFG) * SYZc
                          + ((s.z >> 1) + HALFG) * SZc + ((s.w >> 1) + HALFG);
                if (rcode == tcode) {
                    int pos = atomicAdd(&p.cntk[k], 1);
                    if (pos < CAPK) { p.bkUid[k * CAPK + pos] = (int)uid; p.bkP[k * CAPK + pos] = row; }
                    break;
                }
            }
            slot = (slot + 1) & TBMASK;
        }
    }
}

__device__ __forceinline__ void d_pair(const MegaP& p, int i) {
    int uid = p.tabA[p.slotA[i]].y;
    if (!p.hmark[uid]) return;
    int b = i / PP;
    int pp = i - b * PP;
    int pos = atomicAdd(&p.pcnt[pp], 1);
    if (pos < CAPP) p.pairPack[pp * CAPP + pos] = (b << 18) | uid;
}

__global__ __launch_bounds__(256, 4) void k_mega(MegaP p) {
    cg::grid_group grid = cg::this_grid();
    const int gid = blockIdx.x, t = threadIdx.x, G = gridDim.x;
    const int gtid = gid * 256 + t;
    const int gstride = G * 256;
    __shared__ float fs[32][CC];      // 16 KB (conv/pool tiles)
    __shared__ int ish[520];          // scans / ballots / tile indices
    __shared__ float fsh[384];        // stats reduction / bn1 constants

    // ================= phase 0: init workspace =================
    {
        uint4 ff4 = make_uint4(~0u, ~0u, ~0u, ~0u);
        uint4 z4 = make_uint4(0, 0, 0, 0);
        uint4* q;
        q = (uint4*)p.tabB;
        for (int i = gtid; i < TBSLOTS / 4; i += gstride) q[i] = ff4;
        q = (uint4*)p.colKV;
        for (int i = gtid; i < CHSLOTS / 4; i += gstride) q[i] = ff4;
        q = (uint4*)p.tabA;
        for (int i = gtid; i < TASLOTS / 2; i += gstride) q[i] = ff4;
        q = (uint4*)p.colBM;
        for (int i = gtid; i < CHSLOTS * 3; i += gstride) q[i] = z4;   // 6*u64 = 3*uint4
        q = (uint4*)p.hmark;
        for (int i = gtid; i < p.N / 4; i += gstride) q[i] = z4;
        q = (uint4*)p.pooled;
        for (int i = gtid; i < p.NB * CC / 4; i += gstride) q[i] = z4;
        if (gtid < 128) { p.cntk[gtid] = 0; p.gsum[gtid] = 0.f; p.gsumsq[gtid] = 0.f; }
        if (gtid < 344) p.pcnt[gtid] = 0;
    }
    grid.sync();

    // ================= phase 1: build sp tables + insert grid voxels =================
    {
        int tot = p.Nv + p.N;
        for (int i = gtid; i < tot; i += gstride) {
            if (i < p.Nv) d_build(p, i);
            else          d_insertA(p, i - p.Nv);
        }
    }
    grid.sync();

    // ================= phase 2: per-virtual-block occupied counts (tabA) =================
    for (int vb = gid; vb < NBLKA; vb += G) {
        int s = vb * 256 + t;
        bool occ = p.tabA[s].x != -1;
        u64 m = __ballot(occ);
        if ((t & 63) == 0) ish[512 + (t >> 6)] = __popcll(m);
        __syncthreads();
        if (t == 0) p.blockCnt[vb] = ish[512] + ish[513] + ish[514] + ish[515];
        __syncthreads();
    }
    grid.sync();

    // ================= phase 3: redundant scan + assign uids =================
    int nq_r;
    {
        int c8[8]; int s = 0;
        #pragma unroll
        for (int j = 0; j < 8; j++) { c8[j] = p.blockCnt[t * 8 + j]; s += c8[j]; }
        ish[t] = s;
        __syncthreads();
        for (int o = 1; o < 256; o <<= 1) {
            int v = (t >= o) ? ish[t - o] : 0;
            __syncthreads();
            ish[t] += v;
            __syncthreads();
        }
        int thrBase = ish[t] - s;
        nq_r = ish[255];
        __syncthreads();
        ish[256 + t] = thrBase;
        __syncthreads();
        for (int vb = gid; vb < NBLKA; vb += G) {
            int t0 = vb >> 3, off = vb & 7;
            int base = ish[256 + t0];
            for (int j = 0; j < off; j++) base += p.blockCnt[t0 * 8 + j];
            int sIdx = vb * 256 + t;
            int code = p.tabA[sIdx].x;
            bool occ = code != -1;
            u64 m = __ballot(occ);
            if ((t & 63) == 0) ish[512 + (t >> 6)] = __popcll(m);
            __syncthreads();
            int b2 = base;
            for (int i2 = 0; i2 < (t >> 6); i2++) b2 += ish[512 + i2];
            if (occ) {
                int uid = b2 + __popcll(m & ((1ull << (t & 63)) - 1ull));
                p.tabA[sIdx].y = uid;
                p.ucode[uid] = code;
            }
            __syncthreads();
        }
    }
    grid.sync();

    // ================= phase 4: probe 25 columns per unique voxel =================
    {
        long tot = (long)nq_r * 25;
        for (long idx = gtid; idx < tot; idx += gstride)
            d_probe(p, (unsigned)(idx / 25), (int)(idx % 25));
    }
    grid.sync();

    // ================= phase 5: per-virtual-block hit counts =================
    const int NBH = (p.N + 255) >> 8;
    for (int vb = gid; vb < NBH; vb += G) {
        int i = vb * 256 + t;
        bool h = (i < p.N) && p.hmark[i];
        u64 m = __ballot(h);
        if ((t & 63) == 0) ish[512 + (t >> 6)] = __popcll(m);
        __syncthreads();
        if (t == 0) p.bcntH[vb] = ish[512] + ish[513] + ish[514] + ish[515];
        __syncthreads();
    }
    grid.sync();

    // ================= phase 6: scan + hit list + zero acc rows =================
    int nh_r;
    {
        int c3[3]; int s = 0;
        #pragma unroll
        for (int j = 0; j < 3; j++) {
            int idx = t * 3 + j;
            c3[j] = (idx < NBH) ? p.bcntH[idx] : 0;
            s += c3[j];
        }
        ish[t] = s;
        __syncthreads();
        for (int o = 1; o < 256; o <<= 1) {
            int v = (t >= o) ? ish[t - o] : 0;
            __syncthreads();
            ish[t] += v;
            __syncthreads();
        }
        int thrBase = ish[t] - s;
        nh_r = ish[255];
        __syncthreads();
        ish[256 + t] = thrBase;
        __syncthreads();
        for (int vb = gid; vb < NBH; vb += G) {
            int t0 = vb / 3, off = vb - t0 * 3;
            int base = ish[256 + t0];
            for (int j = 0; j < off; j++) base += p.bcntH[t0 * 3 + j];
            int i = vb * 256 + t;
            bool h = (i < p.N) && p.hmark[i];
            u64 m = __ballot(h);
            if ((t & 63) == 0) ish[512 + (t >> 6)] = __popcll(m);
            __syncthreads();
            int b2 = base;
            for (int i2 = 0; i2 < (t >> 6); i2++) b2 += ish[512 + i2];
            if (h) {
                int pos = b2 + __popcll(m & ((1ull << (t & 63)) - 1ull));
                p.hitList[pos] = i;
                float4* a4 = (float4*)(p.acc + (size_t)i * CC);
                float4 z4 = make_float4(0.f, 0.f, 0.f, 0.f);
                #pragma unroll
                for (int c = 0; c < CC / 4; c++) a4[c] = z4;
            }
            __syncthreads();
        }
    }
    grid.sync();

    // ================= phase 7: sparse conv =================
    for (int vb = gid; vb < 125 * 2 * 3; vb += G) {
        int k = vb % 125;
        int rest = vb / 125;                 // 0..5
        int cob = (rest & 1) * 64;
        int zt = rest >> 1;                  // 0..2
        int co = cob + (t & 63);
        int lane = t >> 6;
        int cnt = min(p.cntk[k], CAPK);
        const float* Wk = p.W1 + (size_t)k * CC * CC;
        for (int tile = zt * 32; tile < cnt; tile += 96) {
            int nt = min(32, cnt - tile);
            if (t < nt) ish[t] = p.bkUid[k * CAPK + tile + t];
            for (int e = t; e < 32 * CC; e += 256) {
                int r = e >> 7, cc = e & 127;
                fs[r][cc] = (r < nt) ? p.spf[(size_t)p.bkP[k * CAPK + tile + r] * CC + cc] : 0.f;
            }
            __syncthreads();
            float a[8] = {0.f, 0.f, 0.f, 0.f, 0.f, 0.f, 0.f, 0.f};
            for (int ci = 0; ci < CC; ci++) {
                float wv = Wk[(size_t)ci * CC + co];
                #pragma unroll
                for (int j = 0; j < 8; j++) a[j] += fs[lane * 8 + j][ci] * wv;
            }
            #pragma unroll
            for (int j = 0; j < 8; j++) {
                int r = lane * 8 + j;
                if (r < nt) atomicAdd(&p.acc[(size_t)ish[r] * CC + co], a[j]);
            }
            __syncthreads();
        }
    }
    grid.sync();

    // ================= phase 8: BN1 stats over hit rows =================
    if (gid < 256) {
        int c = t & 127, half = t >> 7;
        float s = 0.f, s2 = 0.f;
        for (int j = gid * 2 + half; j < nh_r; j += 512) {
            int r = p.hitList[j];
            float v = p.acc[(size_t)r * CC + c];
            s += v; s2 += v * v;
        }
        fsh[t] = s; __syncthreads();
        if (half == 0) atomicAdd(&p.gsum[c], s + fsh[t + 128]);
        __syncthreads();
        fsh[t] = s2; __syncthreads();
        if (half == 0) atomicAdd(&p.gsumsq[c], s2 + fsh[t + 128]);
    }
    grid.sync();

    // ================= phase 9: bn1 (redundant per block) + dx =================
    {
        if (t < 128) {
            float n = (float)max(nq_r, 1);
            float mean = p.gsum[t] / n;
            float var = p.gsumsq[t] / n - mean * mean;
            float rs = 1.0f / sqrtf(var + EPSc);
            float rsg = rs * p.g1[t];
            float c0 = (0.f - mean) * rsg + p.b1[t];
            c0 = c0 > 0.f ? c0 : expm1f(c0);
            fsh[t] = rsg;                       // A
            fsh[128 + t] = p.b1[t] - mean * rsg; // B
            fsh[256 + t] = c0;
        }
        __syncthreads();
        int total = nh_r * 32;
        for (int e = gtid; e < total; e += gstride) {
            int r = p.hitList[e >> 5];
            int c4 = (e & 31) * 4;
            float4* q = (float4*)(p.acc + (size_t)r * CC + c4);
            float4 v = *q;
            float o[4] = {v.x, v.y, v.z, v.w};
            #pragma unroll
            for (int j = 0; j < 4; j++) {
                int c = c4 + j;
                float x = o[j] * fsh[c] + fsh[128 + c];
                x = x > 0.f ? x : expm1f(x);
                o[j] = x - fsh[256 + c];
            }
            *q = make_float4(o[0], o[1], o[2], o[3]);
        }
    }
    grid.sync();

    // ================= phase 10: build (b,p,uid) pairs =================
    for (int i = gtid; i < p.N; i += gstride) d_pair(p, i);
    grid.sync();

    // ================= phase 11: sparse pooling =================
    for (int vb = gid; vb < PP * 2; vb += G) {
        int pp = vb % PP;
        int cob = (vb / PP) * 64;
        int co = cob + (t & 63);
        int lane = t >> 6;
        int cnt = min(p.pcnt[pp], CAPP);
        const float* Wp = p.W2 + (size_t)pp * CC * CC;
        for (int tile = 0; tile < cnt; tile += 32) {
            int nt = min(32, cnt - tile);
            if (t < nt) ish[t] = p.pairPack[pp * CAPP + tile + t] >> 18;
            for (int e = t; e < 32 * CC; e += 256) {
                int r = e >> 7, cc = e & 127;
                float v = 0.f;
                if (r < nt) {
                    int uid = p.pairPack[pp * CAPP + tile + r] & 0x3FFFF;
                    v = p.acc[(size_t)uid * CC + cc];
                }
                fs[r][cc] = v;
            }
            __syncthreads();
            float a[8] = {0.f, 0.f, 0.f, 0.f, 0.f, 0.f, 0.f, 0.f};
            for (int ci = 0; ci < CC; ci++) {
                float wv = Wp[(size_t)ci * CC + co];
                #pragma unroll
                for (int j = 0; j < 8; j++) a[j] += fs[lane * 8 + j][ci] * wv;
            }
            #pragma unroll
            for (int j = 0; j < 8; j++) {
                int r = lane * 8 + j;
                if (r < nt) atomicAdd(&p.pooled[(size_t)ish[r] * CC + co], a[j]);
            }
            __syncthreads();
        }
    }
    grid.sync();

    // ================= phase 12: final BN over rois =================
    if (gid < CC && t < 64) {
        int d = gid;
        int NB = p.NB;
        float s = 0.f;
        for (int b = t; b < NB; b += 64) s += p.pooled[(size_t)b * CC + d];
        for (int o = 32; o >= 1; o >>= 1) s += __shfl_xor(s, o, 64);
        float mean = s / (float)NB;
        float s2 = 0.f;
        for (int b = t; b < NB; b += 64) {
            float v = p.pooled[(size_t)b * CC + d] - mean;
            s2 += v * v;
        }
        for (int o = 32; o >= 1; o >>= 1) s2 += __shfl_xor(s2, o, 64);
        float rs = 1.0f / sqrtf(s2 / (float)NB + EPSc);
        float gg = p.g2[d], bb = p.b2[d];
        for (int b = t; b < NB; b += 64)
            p.out[(size_t)b * CC + d] = (p.pooled[(size_t)b * CC + d] - mean) * rs * gg + bb;
    }
}

extern "C" void kernel_launch(void* const* d_in, const int* in_sizes, int n_in,
                              void* d_out, int out_size, void* d_ws, size_t ws_size,
                              hipStream_t stream) {
    (void)n_in; (void)out_size; (void)ws_size;
    MegaP p;
    p.spc4 = (const int4*)d_in[0];
    p.spf  = (const float*)d_in[1];
    p.gp   = (const float*)d_in[2];
    p.W1   = (const float*)d_in[3];
    p.g1   = (const float*)d_in[4];
    p.b1   = (const float*)d_in[5];
    p.W2   = (const float*)d_in[6];
    p.g2   = (const float*)d_in[7];
    p.b2   = (const float*)d_in[8];
    p.out  = (float*)d_out;
    p.Nv = in_sizes[0] / 4;
    p.N  = in_sizes[2] / 4;
    p.NB = p.N / PP;

    char* w = (char*)d_ws;
    p.tabB  = (unsigned*)w; w += (size_t)TBSLOTS * 4;        // 4 MB
    p.colKV = (unsigned*)w; w += (size_t)CHSLOTS * 4;        // 2 MB
    p.tabA  = (int2*)w;     w += (size_t)TASLOTS * 8;        // 4 MB
    p.colBM = (u64*)w;      w += (size_t)CHSLOTS * 6 * 8;    // 24 MB
    p.cntk  = (int*)w;      w += 128 * 4;
    p.pcnt  = (int*)w;      w += 344 * 4;
    p.gsum  = (float*)w;    w += 128 * 4;
    p.gsumsq= (float*)w;    w += 128 * 4;
    p.hmark = (int*)w;      w += (size_t)p.N * 4;
    p.pooled= (float*)w;    w += (size_t)p.NB * CC * 4;
    p.blockCnt = (int*)w;   w += NBLKA * 4;
    p.bcntH = (int*)w;      w += 1024 * 4;
    p.hitList = (int*)w;    w += (size_t)p.N * 4;
    p.ucode = (int*)w;      w += (size_t)p.N * 4;
    p.slotA = (int*)w;      w += (size_t)p.N * 4;
    p.bkUid = (int*)w;      w += (size_t)KK * CAPK * 4;
    p.bkP   = (int*)w;      w += (size_t)KK * CAPK * 4;
    p.pairPack = (int*)w;   w += (size_t)PP * CAPP * 4;
    p.acc   = (float*)w;    w += (size_t)p.N * CC * 4;

    int maxB = 0;
    hipOccupancyMaxActiveBlocksPerMultiprocessor(&maxB, k_mega, 256, 0);
    if (maxB < 1) maxB = 1;
    int G = maxB * 256;
    if (G > 768) G = 768;
    if (G < 256) G = 256;

    void* args[] = { (void*)&p };
    hipLaunchCooperativeKernel((const void*)k_mega, dim3(G), dim3(256), args, 0, stream);
}